// Round 8
// baseline (143.942 us; speedup 1.0000x reference)
//
#include <hip/hip_runtime.h>

typedef __attribute__((ext_vector_type(8))) short short8;
typedef __attribute__((ext_vector_type(4))) float f32x4;

#define CM 256
#define CC 32
#define CZ 128
#define SDIM 128
#define IDIM 256

__device__ __forceinline__ unsigned short f2bf(float f) {
  union { float f; unsigned u; } v; v.f = f;
  unsigned r = v.u + 0x7fffu + ((v.u >> 16) & 1u);
  return (unsigned short)(r >> 16);
}
// pack two f32 -> two bf16 (round-half-up)
__device__ __forceinline__ unsigned pack_bf2(float a, float b) {
  union { float f; unsigned u; } x, y; x.f = a; y.f = b;
  return ((x.u + 0x8000u) >> 16) | ((y.u + 0x8000u) & 0xffff0000u);
}

// ---------------- kernel 0: weight prep ----------------
// wlrT2 fragment-major: wlrT2[((nt*8+ks)*64+lane)*8+e] = Wlr[c64=nt*16+ln][cm=ks*32+qd*8+e]
// WF fragment-major: WF[((zt*32+ks)*64+lane)*8+e]; lane(qd,ln) holds
//   W[z=zt*16+ln][kappa=ks*32+qd*8+e]/128, kappa=d*32+c (d=ks, c=qd*8+e)
__global__ void k_prep(const float* __restrict__ wl, const float* __restrict__ wr,
                       const float* __restrict__ wo,
                       unsigned short* __restrict__ wlrT2, unsigned short* __restrict__ WF) {
  int t = blockIdx.x * 256 + threadIdx.x;
  if (t < 2048) {
    int frag = t >> 6, lane = t & 63;
    int nt = frag >> 3, ks = frag & 7;
    int ln = lane & 15, qd = lane >> 4;
    int c64 = nt * 16 + ln;
#pragma unroll
    for (int e = 0; e < 8; ++e) {
      int cm = ks * 32 + qd * 8 + e;
      float v = (c64 < CC) ? wl[cm * CC + c64] : wr[cm * CC + (c64 - CC)];
      wlrT2[(size_t)t * 8 + e] = f2bf(v);
    }
  } else {
    int t2 = t - 2048;
    if (t2 < 8 * 32 * 64) {
      int zt = t2 >> 11, ks = (t2 >> 6) & 31, lane = t2 & 63;
      int ln = lane & 15, qd = lane >> 4;
      int z = zt * 16 + ln;
#pragma unroll
      for (int e = 0; e < 8; ++e) {
        int c = qd * 8 + e, d = ks;
        WF[(size_t)t2 * 8 + e] = f2bf(wo[(c * 32 + d) * CZ + z] * (1.0f / 128.0f));
      }
    }
  }
}

// ---------------- kernel 1: LayerNorm + dual projection ----------------
// Block (i, sh): 512 blocks x 256 threads (4 waves); s-range = [sh*64, +64).
__global__ __launch_bounds__(256) void k_lnproj(
    const float* __restrict__ x, const float* __restrict__ lnw, const float* __restrict__ lnb,
    const float* __restrict__ bl, const float* __restrict__ br,
    const unsigned short* __restrict__ wlrT2,
    unsigned short* __restrict__ A2, unsigned short* __restrict__ Bbuf) {
  __shared__ __align__(16) unsigned short xn[64][264];
  __shared__ __align__(16) unsigned short sT[64][72];
  int tid = threadIdx.x;
  int lane = tid & 63, ww = tid >> 6;
  int qd = lane >> 4, ln = lane & 15;
  int i = blockIdx.x, sh = blockIdx.y;

  for (int rr = 0; rr < 16; ++rr) {
    int sl = ww * 16 + rr;
    int s = sh * 64 + sl;
    float4 v = ((const float4*)(x + ((size_t)s * IDIM + i) * CM))[lane];
    float s1 = v.x + v.y + v.z + v.w;
    float s2 = v.x * v.x + v.y * v.y + v.z * v.z + v.w * v.w;
#pragma unroll
    for (int off = 32; off; off >>= 1) {
      s1 += __shfl_xor(s1, off);
      s2 += __shfl_xor(s2, off);
    }
    float mu = s1 * (1.0f / 256.0f);
    float var = s2 * (1.0f / 256.0f) - mu * mu;
    float rs = rsqrtf(var + 1e-5f);
    float4 w4 = ((const float4*)lnw)[lane];
    float4 b4 = ((const float4*)lnb)[lane];
    ushort4 h;
    h.x = f2bf((v.x - mu) * rs * w4.x + b4.x);
    h.y = f2bf((v.y - mu) * rs * w4.y + b4.y);
    h.z = f2bf((v.z - mu) * rs * w4.z + b4.z);
    h.w = f2bf((v.w - mu) * rs * w4.w + b4.w);
    *(ushort4*)&xn[sl][lane * 4] = h;
  }
  __syncthreads();

  f32x4 acc[4];
#pragma unroll
  for (int nt = 0; nt < 4; ++nt) acc[nt] = (f32x4){0.f, 0.f, 0.f, 0.f};
#pragma unroll
  for (int ks = 0; ks < 8; ++ks) {
    short8 af = *(const short8*)&xn[ww * 16 + ln][ks * 32 + qd * 8];
#pragma unroll
    for (int nt = 0; nt < 4; ++nt) {
      short8 bf = *(const short8*)(wlrT2 + ((size_t)((nt * 8 + ks) * 64 + lane)) * 8);
      acc[nt] = __builtin_amdgcn_mfma_f32_16x16x32_bf16(af, bf, acc[nt], 0, 0, 0);
    }
  }
#pragma unroll
  for (int nt = 0; nt < 4; ++nt) {
    int c64 = nt * 16 + ln;
    float bias = (c64 < CC) ? bl[c64] : br[c64 - CC];
    ushort4 h;
    h.x = f2bf(acc[nt][0] + bias);
    h.y = f2bf(acc[nt][1] + bias);
    h.z = f2bf(acc[nt][2] + bias);
    h.w = f2bf(acc[nt][3] + bias);
    *(ushort4*)&sT[c64][ww * 16 + qd * 4] = h;
  }
  __syncthreads();

  {
    int rtloc = ww >> 1, ksl = ww & 1;
    short8 v = *(const short8*)&sT[rtloc * 16 + ln][ksl * 32 + qd * 8];
    *(short8*)(A2 + ((size_t)(((2 * i + rtloc) * 4 + (sh * 2 + ksl)) * 64 + lane)) * 8) = v;
  }
  {
    int row = tid >> 3, ch = tid & 7;
    short8 v = *(const short8*)&sT[CC + row][ch * 8];
    *(short8*)(Bbuf + ((size_t)(i * CC + row)) * SDIM + sh * 64 + ch * 8) = v;
  }
}

// ---------------- kernel 2: fused outer-product + output projection ----------------
// Block = 8i x 4j = 32 pairs, 512 threads (8 waves), 2048 blocks, LDS 66 KB -> 2 blocks/CU.
// p1 (waves wy4 x wx2): P[256][128] = A@B^T, K=128; A-frags global (A2), B from LDS.
// P -> sP bf16 full-kappa [32][1032] (overlays sB), proven 2-way swizzle.
// p2 (waves ztg2 x kq4): operand-swapped mfma(W,P) -> D[z][p]; acc2[4 zt][2 mt];
//   afr redundancy 2, WF 32KB/wave. kq-4 tree reduction in lane-linear 8KB slots.
__global__ __launch_bounds__(512, 4) void k_main(
    const unsigned short* __restrict__ A2, const unsigned short* __restrict__ Bbuf,
    const unsigned short* __restrict__ WF, const float* __restrict__ bout,
    float* __restrict__ out) {
  extern __shared__ __align__(16) char lds[];
  unsigned short* sB = (unsigned short*)lds;   // [128][136] = 34,816 B
  unsigned short* sP = (unsigned short*)lds;   // [32][1032] = 66,048 B (overlay after p1)
  float* redF = (float*)lds;                   // 4 slots x 8 KB (overlay after p2)
  int tid = threadIdx.x;
  int lane = tid & 63, ww = tid >> 6;
  int qd = lane >> 4, ln = lane & 15;
  int i0 = blockIdx.x * 8, j0 = blockIdx.y * 4;

  // stage B tile: rows j0*32 .. +127, K=128
#pragma unroll
  for (int t = 0; t < 4; ++t) {
    int idx = tid + t * 512;
    int r = idx >> 4, ch = idx & 15;
    short8 v = *(const short8*)(Bbuf + (size_t)(j0 * CC + r) * SDIM + ch * 8);
    *(short8*)&sB[r * 136 + ch * 8] = v;
  }
  __syncthreads();

  // phase 1: wave (wy = ww>>1 in 0..3, wx = ww&1): 64x64 region
  int wy = ww >> 1, wx = ww & 1;
  f32x4 acc1[4][4];
#pragma unroll
  for (int a = 0; a < 4; ++a)
#pragma unroll
    for (int b = 0; b < 4; ++b) acc1[a][b] = (f32x4){0.f, 0.f, 0.f, 0.f};
#pragma unroll
  for (int ks = 0; ks < 4; ++ks) {
    short8 af[4];
#pragma unroll
    for (int ti = 0; ti < 4; ++ti)
      af[ti] = *(const short8*)(A2 + ((size_t)((i0 * 2 + wy * 4 + ti) * 4 + ks) * 64 + lane) * 8);
#pragma unroll
    for (int tj = 0; tj < 4; ++tj) {
      short8 bf = *(const short8*)&sB[(wx * 64 + tj * 16 + ln) * 136 + ks * 32 + qd * 8];
#pragma unroll
      for (int ti = 0; ti < 4; ++ti)
        acc1[ti][tj] = __builtin_amdgcn_mfma_f32_16x16x32_bf16(af[ti], bf, acc1[ti][tj], 0, 0, 0);
    }
  }
  __syncthreads();  // all sB reads done; sP overlay safe

  // P write: pair p = iloc*4 + jloc (iloc 0..7, jloc 0..3); proven swizzle
#pragma unroll
  for (int ti = 0; ti < 4; ++ti) {
    int iloc = wy * 2 + (ti >> 1);
    int cbase = 16 * (ti & 1) + qd * 4;
    int cb = cbase >> 3;
#pragma unroll
    for (int tj = 0; tj < 4; ++tj) {
      int jloc = wx * 2 + (tj >> 1);
      int d = 16 * (tj & 1) + ln;
      int p = iloc * 4 + jloc;
      uint2 u;
      u.x = pack_bf2(acc1[ti][tj][0], acc1[ti][tj][1]);
      u.y = pack_bf2(acc1[ti][tj][2], acc1[ti][tj][3]);
      *(uint2*)&sP[p * 1032 + d * 32 + ((((d >> 1) & 3) ^ cb) * 8) + (cbase & 7)] = u;
    }
  }
  __syncthreads();

  // phase 2: ztg = ww>>2 (zt = ztg*4+z4), kq = ww&3 (8 kappa-chunks each)
  int ztg = ww >> 2, kq = ww & 3;
  f32x4 acc2[4][2];  // [z4][mt]
#pragma unroll
  for (int a = 0; a < 4; ++a)
#pragma unroll
    for (int b = 0; b < 2; ++b) acc2[a][b] = (f32x4){0.f, 0.f, 0.f, 0.f};
#pragma unroll
  for (int cc = 0; cc < 8; ++cc) {
    int ks = kq * 8 + cc;
    short8 afr[2];
#pragma unroll
    for (int mt = 0; mt < 2; ++mt)
      afr[mt] = *(const short8*)&sP[(mt * 16 + ln) * 1032 + ks * 32 + ((((ks >> 1) & 3) ^ qd) * 8)];
#pragma unroll
    for (int z4 = 0; z4 < 4; ++z4) {
      int zt = ztg * 4 + z4;
      short8 bfr = *(const short8*)(WF + ((size_t)(zt * 32 + ks) * 64 + lane) * 8);
#pragma unroll
      for (int mt = 0; mt < 2; ++mt)  // SWAPPED operands: D[m=z][n=p]
        acc2[z4][mt] = __builtin_amdgcn_mfma_f32_16x16x32_bf16(bfr, afr[mt], acc2[z4][mt], 0, 0, 0);
    }
  }

  // kq-4 tree reduction; slot s = 2048 floats, lane-linear:
  //   addr = s*2048 + ((z4*2+mt)<<8) + lane*4
  __syncthreads();  // all sP reads done; redF overlay safe
  if (kq >= 2) {
    int s = (kq - 2) * 2 + ztg;
#pragma unroll
    for (int z4 = 0; z4 < 4; ++z4)
#pragma unroll
      for (int mt = 0; mt < 2; ++mt)
        *(f32x4*)&redF[s * 2048 + ((z4 * 2 + mt) << 8) + lane * 4] = acc2[z4][mt];
  }
  __syncthreads();
  if (kq < 2) {
    int s = kq * 2 + ztg;  // kq0 <- kq2's slot(ztg), kq1 <- kq3's slot(2+ztg)
#pragma unroll
    for (int z4 = 0; z4 < 4; ++z4)
#pragma unroll
      for (int mt = 0; mt < 2; ++mt)
        acc2[z4][mt] += *(const f32x4*)&redF[s * 2048 + ((z4 * 2 + mt) << 8) + lane * 4];
  }
  __syncthreads();
  if (kq == 1) {
#pragma unroll
    for (int z4 = 0; z4 < 4; ++z4)
#pragma unroll
      for (int mt = 0; mt < 2; ++mt)
        *(f32x4*)&redF[ztg * 2048 + ((z4 * 2 + mt) << 8) + lane * 4] = acc2[z4][mt];
  }
  __syncthreads();
  if (kq == 0) {
#pragma unroll
    for (int z4 = 0; z4 < 4; ++z4) {
      int z = (ztg * 4 + z4) * 16 + qd * 4;
      f32x4 bz = *(const f32x4*)(bout + z);
#pragma unroll
      for (int mt = 0; mt < 2; ++mt) {
        int p = mt * 16 + ln;
        f32x4 v = acc2[z4][mt] +
                  *(const f32x4*)&redF[ztg * 2048 + ((z4 * 2 + mt) << 8) + lane * 4] + bz;
        int i = i0 + (p >> 2), j = j0 + (p & 3);
        *(f32x4*)&out[((size_t)i * IDIM + j) * CZ + z] = v;
      }
    }
  }
}

extern "C" void kernel_launch(void* const* d_in, const int* in_sizes, int n_in,
                              void* d_out, int out_size, void* d_ws, size_t ws_size,
                              hipStream_t stream) {
  const float* msa = (const float*)d_in[0];
  const float* lnw = (const float*)d_in[1];
  const float* lnb = (const float*)d_in[2];
  const float* wl  = (const float*)d_in[3];
  const float* bl  = (const float*)d_in[4];
  const float* wr  = (const float*)d_in[5];
  const float* br  = (const float*)d_in[6];
  const float* wo  = (const float*)d_in[7];
  const float* bo  = (const float*)d_in[8];
  float* out = (float*)d_out;

  char* ws = (char*)d_ws;
  unsigned short* A2    = (unsigned short*)ws;                         // 2 MB (frag-major)
  unsigned short* Bbuf  = (unsigned short*)(ws + (2u << 20));          // 2 MB (row-major)
  unsigned short* wlrT2 = (unsigned short*)(ws + (4u << 20));          // 32 KB (frag-major)
  unsigned short* WF    = (unsigned short*)(ws + (4u << 20) + 32768);  // 256 KB

  (void)hipFuncSetAttribute((const void*)k_main,
                            hipFuncAttributeMaxDynamicSharedMemorySize, 66048);

  k_prep<<<72, 256, 0, stream>>>(wl, wr, wo, wlrT2, WF);
  k_lnproj<<<dim3(256, 2), 256, 0, stream>>>(msa, lnw, lnb, bl, br, wlrT2, A2, Bbuf);
  k_main<<<dim3(32, 64), 512, 66048, stream>>>(A2, Bbuf, WF, bo, out);
}